// Round 1
// baseline (3021.184 us; speedup 1.0000x reference)
//
#include <hip/hip_runtime.h>

// CNN4d: embed -> 3x (conv4d 5^4 + BN(train stats) + LeakyReLU) -> proj
// Layout: activations channel-interleaved [v][c], v = ((t*24+x)*24+y)*12+z
// Weights pre-transposed to [tap][ci][co] for wave-uniform scalar reads.

#define TDIM 6
#define XDIM 24
#define YDIM 24
#define ZDIM 12
#define VOL 41472   // 6*24*24*12
#define EPSV 1e-5f
#define SLOPE 0.1f

// ---------------- embed: out[v*16+h] = sum_f x[v*8+f]*w[f*16+h] + b[h] ----
__global__ __launch_bounds__(256) void embed_kernel(
    const float* __restrict__ x, const float* __restrict__ w,
    const float* __restrict__ b, float* __restrict__ out) {
  int v = blockIdx.x * 256 + threadIdx.x;          // grid covers VOL exactly
  float acc[16];
  #pragma unroll
  for (int h = 0; h < 16; ++h) acc[h] = b[h];
  const float4* xp = reinterpret_cast<const float4*>(x + (size_t)v * 8);
  float4 x0 = xp[0], x1 = xp[1];
  float xv[8] = {x0.x, x0.y, x0.z, x0.w, x1.x, x1.y, x1.z, x1.w};
  #pragma unroll
  for (int f = 0; f < 8; ++f) {
    #pragma unroll
    for (int h = 0; h < 16; ++h)
      acc[h] = fmaf(xv[f], w[f * 16 + h], acc[h]);
  }
  float4* op = reinterpret_cast<float4*>(out + (size_t)v * 16);
  op[0] = make_float4(acc[0], acc[1], acc[2], acc[3]);
  op[1] = make_float4(acc[4], acc[5], acc[6], acc[7]);
  op[2] = make_float4(acc[8], acc[9], acc[10], acc[11]);
  op[3] = make_float4(acc[12], acc[13], acc[14], acc[15]);
}

// ---------------- weight transpose: wt[(tap*CIN+ci)*COUT+co] = w[(co*CIN+ci)*625+tap]
template<int CIN, int COUT>
__global__ __launch_bounds__(256) void wtrans_kernel(
    const float* __restrict__ w, float* __restrict__ wt) {
  int i = blockIdx.x * 256 + threadIdx.x;          // grid covers total exactly
  int co = i % COUT;
  int ci = (i / COUT) % CIN;
  int tap = i / (COUT * CIN);
  wt[i] = w[(co * CIN + ci) * 625 + tap];
}

// ---------------- direct conv4d, cross-correlation, pad 2 ----------------
template<int CIN, int COUT, int COPER>
__global__ __launch_bounds__(64) void conv4d_kernel(
    const float* __restrict__ in, const float* __restrict__ wt,
    const float* __restrict__ bias, float* __restrict__ out) {
  int v = blockIdx.x * 64 + threadIdx.x;           // t,x uniform per wave (64 | 288)
  int co0 = blockIdx.y * COPER;
  int z = v % ZDIM;
  int y = (v / ZDIM) % YDIM;
  int xx = (v / (ZDIM * YDIM)) % XDIM;
  int t = v / (ZDIM * YDIM * XDIM);
  float acc[COPER];
  #pragma unroll
  for (int c = 0; c < COPER; ++c) acc[c] = 0.f;

  for (int dt = 0; dt < 5; ++dt) {
    int ti = t + dt - 2;
    if ((unsigned)ti >= TDIM) continue;            // wave-uniform skip
    for (int dx = 0; dx < 5; ++dx) {
      int xi = xx + dx - 2;
      if ((unsigned)xi >= XDIM) continue;          // wave-uniform skip
      for (int dy = 0; dy < 5; ++dy) {
        int yi = y + dy - 2;
        bool oky = (unsigned)yi < YDIM;
        if (!__any(oky)) continue;
        for (int dz = 0; dz < 5; ++dz) {
          int zi = z + dz - 2;
          bool ok = oky && ((unsigned)zi < ZDIM);
          int tap = ((dt * 5 + dx) * 5 + dy) * 5 + dz;
          const float* wp = wt + (size_t)tap * (CIN * COUT) + co0;
          float xin[CIN];
          if (ok) {
            const float4* p = reinterpret_cast<const float4*>(
                in + (size_t)(((ti * XDIM + xi) * YDIM + yi) * ZDIM + zi) * CIN);
            #pragma unroll
            for (int q = 0; q < CIN / 4; ++q) {
              float4 f4 = p[q];
              xin[4*q+0] = f4.x; xin[4*q+1] = f4.y;
              xin[4*q+2] = f4.z; xin[4*q+3] = f4.w;
            }
          } else {
            #pragma unroll
            for (int q = 0; q < CIN; ++q) xin[q] = 0.f;
          }
          #pragma unroll
          for (int ci = 0; ci < CIN; ++ci) {
            #pragma unroll
            for (int c = 0; c < COPER; ++c)
              acc[c] = fmaf(wp[ci * COUT + c], xin[ci], acc[c]);
          }
        }
      }
    }
  }
  #pragma unroll
  for (int c = 0; c < COPER; ++c) acc[c] += bias[co0 + c];
  #pragma unroll
  for (int c = 0; c < COPER; c += 4) {
    *reinterpret_cast<float4*>(out + (size_t)v * COUT + co0 + c) =
        make_float4(acc[c], acc[c+1], acc[c+2], acc[c+3]);
  }
}

// ---------------- BN stats: one block per channel -------------------------
template<int C>
__global__ __launch_bounds__(256) void bn_stats_kernel(
    const float* __restrict__ a, float* __restrict__ stats) {
  int c = blockIdx.x;
  float s = 0.f, s2 = 0.f;
  for (int i = threadIdx.x; i < VOL; i += 256) {
    float xv = a[(size_t)i * C + c];
    s += xv;
    s2 = fmaf(xv, xv, s2);
  }
  #pragma unroll
  for (int off = 32; off > 0; off >>= 1) {
    s  += __shfl_down(s, off);
    s2 += __shfl_down(s2, off);
  }
  __shared__ float sh[8];
  int wid = threadIdx.x >> 6;
  if ((threadIdx.x & 63) == 0) { sh[wid] = s; sh[4 + wid] = s2; }
  __syncthreads();
  if (threadIdx.x == 0) {
    float S  = sh[0] + sh[1] + sh[2] + sh[3];
    float S2 = sh[4] + sh[5] + sh[6] + sh[7];
    float mean = S * (1.f / VOL);
    float var  = S2 * (1.f / VOL) - mean * mean;
    stats[2 * c] = mean;
    stats[2 * c + 1] = var;
  }
}

// ---------------- BN apply + LeakyReLU ------------------------------------
template<int C>
__global__ __launch_bounds__(256) void bn_apply_kernel(
    const float* __restrict__ a, const float* __restrict__ stats,
    const float* __restrict__ g, const float* __restrict__ be,
    float* __restrict__ out) {
  int i = blockIdx.x * 256 + threadIdx.x;          // grid covers C*VOL exactly
  int c = i & (C - 1);
  float mean = stats[2 * c], var = stats[2 * c + 1];
  float sc = g[c] * rsqrtf(var + EPSV);
  float sh = fmaf(-mean, sc, be[c]);
  float xv = fmaf(a[i], sc, sh);
  out[i] = fmaxf(xv, SLOPE * xv);
}

// ---------------- projection ----------------------------------------------
__global__ __launch_bounds__(256) void proj_kernel(
    const float* __restrict__ a, const float* __restrict__ w,
    const float* __restrict__ b, float* __restrict__ out) {
  int v = blockIdx.x * 256 + threadIdx.x;
  float s = b[0];
  const float4* p = reinterpret_cast<const float4*>(a + (size_t)v * 16);
  #pragma unroll
  for (int q = 0; q < 4; ++q) {
    float4 f4 = p[q];
    s = fmaf(f4.x, w[4*q+0], s);
    s = fmaf(f4.y, w[4*q+1], s);
    s = fmaf(f4.z, w[4*q+2], s);
    s = fmaf(f4.w, w[4*q+3], s);
  }
  out[v] = s;
}

extern "C" void kernel_launch(void* const* d_in, const int* in_sizes, int n_in,
                              void* d_out, int out_size, void* d_ws, size_t ws_size,
                              hipStream_t stream) {
  const float* x      = (const float*)d_in[0];
  const float* w_emb  = (const float*)d_in[1];
  const float* b_emb  = (const float*)d_in[2];
  const float* w1     = (const float*)d_in[3];
  const float* b1     = (const float*)d_in[4];
  const float* g1     = (const float*)d_in[5];
  const float* be1    = (const float*)d_in[6];
  const float* w2     = (const float*)d_in[7];
  const float* b2     = (const float*)d_in[8];
  const float* g2     = (const float*)d_in[9];
  const float* be2    = (const float*)d_in[10];
  const float* w3     = (const float*)d_in[11];
  const float* b3     = (const float*)d_in[12];
  const float* g3     = (const float*)d_in[13];
  const float* be3    = (const float*)d_in[14];
  const float* w_proj = (const float*)d_in[15];
  const float* b_proj = (const float*)d_in[16];

  float* ws  = (float*)d_ws;
  float* A   = ws;                          // 32*VOL floats (act in)
  float* Bf  = ws + (size_t)32 * VOL;       // 32*VOL floats (conv out)
  float* WT  = ws + (size_t)64 * VOL;       // up to 320000 floats
  float* ST  = WT + 320000;                 // 64 floats (mean,var per channel)
  float* out = (float*)d_out;

  embed_kernel<<<VOL / 256, 256, 0, stream>>>(x, w_emb, b_emb, A);

  // layer 1: 16 -> 16
  wtrans_kernel<16, 16><<<625, 256, 0, stream>>>(w1, WT);
  conv4d_kernel<16, 16, 4><<<dim3(VOL / 64, 4), 64, 0, stream>>>(A, WT, b1, Bf);
  bn_stats_kernel<16><<<16, 256, 0, stream>>>(Bf, ST);
  bn_apply_kernel<16><<<16 * VOL / 256, 256, 0, stream>>>(Bf, ST, g1, be1, A);

  // layer 2: 16 -> 32
  wtrans_kernel<16, 32><<<1250, 256, 0, stream>>>(w2, WT);
  conv4d_kernel<16, 32, 8><<<dim3(VOL / 64, 4), 64, 0, stream>>>(A, WT, b2, Bf);
  bn_stats_kernel<32><<<32, 256, 0, stream>>>(Bf, ST);
  bn_apply_kernel<32><<<32 * VOL / 256, 256, 0, stream>>>(Bf, ST, g2, be2, A);

  // layer 3: 32 -> 16
  wtrans_kernel<32, 16><<<1250, 256, 0, stream>>>(w3, WT);
  conv4d_kernel<32, 16, 4><<<dim3(VOL / 64, 4), 64, 0, stream>>>(A, WT, b3, Bf);
  bn_stats_kernel<16><<<16, 256, 0, stream>>>(Bf, ST);
  bn_apply_kernel<16><<<16 * VOL / 256, 256, 0, stream>>>(Bf, ST, g3, be3, A);

  proj_kernel<<<VOL / 256, 256, 0, stream>>>(A, w_proj, b_proj, out);
}

// Round 2
// 304.642 us; speedup vs baseline: 9.9172x; 9.9172x over previous
//
#include <hip/hip_runtime.h>

typedef short short8 __attribute__((ext_vector_type(8)));
typedef float floatx4 __attribute__((ext_vector_type(4)));

#define TDIM 6
#define XDIM 24
#define YDIM 24
#define ZDIM 12
#define VOL 41472   // 6*24*24*12
#define EPSV 1e-5f
#define SLOPE 0.1f

// workspace byte offsets
#define ACT_OFF   0u
#define CONV_OFF  2654208u      // ACT: VOL*32*2 bytes bf16 (max CIN 32)
#define WB_OFF    7962624u      // CONV: VOL*32*4 bytes fp32
#define ZP_OFF    8730624u      // WB: up to 768000 bytes bf16
#define STATS_OFF 8730880u      // ZP: 256 bytes (zero page)
#define PART_OFF  8731392u      // STATS: 512 bytes (sc,sh per channel)
                                // PART: 256*32*2*4 = 65536 bytes

__device__ inline unsigned short f2bf(float f) {
  unsigned u = __builtin_bit_cast(unsigned, f);
  unsigned r = u + 0x7fffu + ((u >> 16) & 1u);
  return (unsigned short)(r >> 16);
}
__device__ inline float bf2f(unsigned short h) {
  unsigned u = ((unsigned)h) << 16;
  return __builtin_bit_cast(float, u);
}

__global__ __launch_bounds__(64) void zero_misc(float* zp) {
  if (threadIdx.x < 16) zp[threadIdx.x] = 0.f;
}

// ---------------- embed: act[v][h] = bf16( sum_f x[v][f]*w[f][h] + b[h] ) --
__global__ __launch_bounds__(256) void embed_kernel(
    const float* __restrict__ x, const float* __restrict__ w,
    const float* __restrict__ b, unsigned short* __restrict__ act) {
  int v = blockIdx.x * 256 + threadIdx.x;
  const float4* xp = reinterpret_cast<const float4*>(x + (size_t)v * 8);
  float4 x0 = xp[0], x1 = xp[1];
  float xv[8] = {x0.x, x0.y, x0.z, x0.w, x1.x, x1.y, x1.z, x1.w};
  float acc[16];
  #pragma unroll
  for (int h = 0; h < 16; ++h) acc[h] = b[h];
  #pragma unroll
  for (int f = 0; f < 8; ++f)
    #pragma unroll
    for (int h = 0; h < 16; ++h)
      acc[h] = fmaf(xv[f], w[f * 16 + h], acc[h]);
  short8 o0, o1;
  #pragma unroll
  for (int h = 0; h < 8; ++h) { o0[h] = (short)f2bf(acc[h]); o1[h] = (short)f2bf(acc[8 + h]); }
  short8* op = reinterpret_cast<short8*>(act + (size_t)v * 16);
  op[0] = o0; op[1] = o1;
}

// ---------------- weight -> B-fragment-ordered bf16 -----------------------
// wb[((dtxy*NP + p)*NCOG + cog)*64 + lane][8]
// k = g*8+j : CIN16: tap_sub=g>>1 (dz=2p+tsub), ci=(g&1)*8+j ; CIN32: ci=g*8+j, dz=p
template<int CIN, int COUT>
__global__ __launch_bounds__(256) void wtrans_mfma(
    const float* __restrict__ w, short8* __restrict__ wb) {
  constexpr int NP = (CIN == 16) ? 3 : 5;
  constexpr int NCOG = COUT / 16;
  int id = blockIdx.x * 256 + threadIdx.x;
  if (id >= 125 * NP * NCOG * 64) return;
  int lane = id & 63;
  int q = id >> 6;
  int cog = q % NCOG; q /= NCOG;
  int p = q % NP; q /= NP;            // q = (dt*5+dx)*5+dy in [0,125)
  int g = lane >> 4, n = lane & 15;
  int co = cog * 16 + n;
  short8 out;
  #pragma unroll
  for (int j = 0; j < 8; ++j) {
    int ci = (CIN == 16) ? ((g & 1) * 8 + j) : (g * 8 + j);
    int dz = (CIN == 16) ? (2 * p + (g >> 1)) : p;
    float val = 0.f;
    if (dz < 5) val = w[((size_t)co * CIN + ci) * 625 + q * 5 + dz];
    out[j] = (short)f2bf(val);
  }
  wb[id] = out;
}

// ---------------- conv4d via MFMA (shifted GEMM) --------------------------
template<int CIN, int COUT>
__global__ __launch_bounds__(64) void conv4d_mfma(
    const unsigned short* __restrict__ act, const short8* __restrict__ wb,
    const float* __restrict__ bias, float* __restrict__ convout,
    const unsigned short* __restrict__ zp) {
  constexpr int NP = (CIN == 16) ? 3 : 5;
  constexpr int NCOG = COUT / 16;
  int l = threadIdx.x;
  int v0 = blockIdx.x * 16;
  int col = l & 15, g = l >> 4;
  int v = v0 + col;                       // A-row voxel for this lane's A frags
  int z = v % ZDIM;
  int y = (v / ZDIM) % YDIM;
  int x = (v / (ZDIM * YDIM)) % XDIM;     // wave-uniform (16 | 288)
  int t = v / (ZDIM * YDIM * XDIM);       // wave-uniform
  int tsub = (CIN == 16) ? (g >> 1) : 0;
  int c0 = (CIN == 16) ? ((g & 1) * 8) : (g * 8);

  unsigned pbits = 0;
  #pragma unroll
  for (int p = 0; p < NP; ++p) {
    int dz = (CIN == 16) ? (2 * p + tsub) : p;
    int zi = z + dz - 2;
    if (dz < 5 && (unsigned)zi < ZDIM) pbits |= (1u << p);
  }

  floatx4 acc[NCOG];
  #pragma unroll
  for (int cg = 0; cg < NCOG; ++cg) acc[cg] = (floatx4){0.f, 0.f, 0.f, 0.f};

  for (int dt = 0; dt < 5; ++dt) {
    int ti = t + dt - 2;
    if ((unsigned)ti >= TDIM) continue;            // wave-uniform
    for (int dx = 0; dx < 5; ++dx) {
      int xi = x + dx - 2;
      if ((unsigned)xi >= XDIM) continue;          // wave-uniform
      // per-lane element offset at dy=0, p=0 (may be negative; only valid derefs)
      int aoff = (((ti * XDIM + xi) * YDIM + (y - 2)) * ZDIM + (z + tsub - 2)) * CIN + c0;
      for (int dy = 0; dy < 5; ++dy, aoff += ZDIM * CIN) {
        int yi = y + dy - 2;
        bool oky = (unsigned)yi < YDIM;
        if (!__any(oky)) continue;
        unsigned m = oky ? pbits : 0u;
        const short8* bptr = wb + ((size_t)(((dt * 5 + dx) * 5 + dy) * NP) * NCOG) * 64 + l;
        #pragma unroll
        for (int p = 0; p < NP; ++p) {
          const short8* ap = ((m >> p) & 1u)
              ? reinterpret_cast<const short8*>(act + aoff + p * 32)
              : reinterpret_cast<const short8*>(zp);
          short8 a = *ap;
          #pragma unroll
          for (int cg = 0; cg < NCOG; ++cg) {
            short8 bf = bptr[(p * NCOG + cg) * 64];
            acc[cg] = __builtin_amdgcn_mfma_f32_16x16x32_bf16(a, bf, acc[cg], 0, 0, 0);
          }
        }
      }
    }
  }
  #pragma unroll
  for (int cg = 0; cg < NCOG; ++cg) {
    int co = cg * 16 + col;
    float bv = bias[co];
    #pragma unroll
    for (int i = 0; i < 4; ++i) {
      int r = g * 4 + i;                 // C row = voxel offset
      convout[(size_t)(v0 + r) * COUT + co] = acc[cg][i] + bv;
    }
  }
}

// ---------------- BN stats stage 1: 256 blocks of partial sums ------------
template<int C>
__global__ __launch_bounds__(256) void bn_stats1(
    const float* __restrict__ a, float* __restrict__ part) {
  int b = blockIdx.x, t = threadIdx.x;
  const int chunk = (VOL / 256) * C;
  size_t base = (size_t)b * chunk;
  float s = 0.f, s2 = 0.f;
  for (int k = t; k < chunk; k += 256) {
    float xv = a[base + k];
    s += xv; s2 = fmaf(xv, xv, s2);
  }
  __shared__ float shs[256], shs2[256];
  shs[t] = s; shs2[t] = s2;
  __syncthreads();
  if (t < C) {
    float S = 0.f, S2 = 0.f;
    for (int j = t; j < 256; j += C) { S += shs[j]; S2 += shs2[j]; }
    part[(size_t)(b * C + t) * 2] = S;
    part[(size_t)(b * C + t) * 2 + 1] = S2;
  }
}

// ---------------- BN stats stage 2: reduce + fold gamma/beta --------------
template<int C>
__global__ __launch_bounds__(64) void bn_stats2(
    const float* __restrict__ part, const float* __restrict__ gam,
    const float* __restrict__ bet, float* __restrict__ stats) {
  int c = threadIdx.x;
  if (c >= C) return;
  float S = 0.f, S2 = 0.f;
  for (int b = 0; b < 256; ++b) {
    S += part[(size_t)(b * C + c) * 2];
    S2 += part[(size_t)(b * C + c) * 2 + 1];
  }
  float mean = S * (1.f / VOL);
  float var = S2 * (1.f / VOL) - mean * mean;
  float sc = gam[c] * rsqrtf(var + EPSV);
  float sh = fmaf(-mean, sc, bet[c]);
  stats[2 * c] = sc;
  stats[2 * c + 1] = sh;
}

// ---------------- BN apply + LeakyReLU -> bf16 act ------------------------
template<int C>
__global__ __launch_bounds__(256) void bn_apply(
    const float* __restrict__ a, const float* __restrict__ stats,
    unsigned short* __restrict__ act) {
  int i = blockIdx.x * 256 + threadIdx.x;     // covers VOL*C/8 exactly
  size_t e = (size_t)i * 8;
  int cb = (int)(e & (C - 1));
  const float4* p = reinterpret_cast<const float4*>(a + e);
  float4 f0 = p[0], f1 = p[1];
  float vv[8] = {f0.x, f0.y, f0.z, f0.w, f1.x, f1.y, f1.z, f1.w};
  short8 o;
  #pragma unroll
  for (int k = 0; k < 8; ++k) {
    float sc = stats[2 * (cb + k)], sh = stats[2 * (cb + k) + 1];
    float xv = fmaf(vv[k], sc, sh);
    xv = fmaxf(xv, SLOPE * xv);
    o[k] = (short)f2bf(xv);
  }
  *reinterpret_cast<short8*>(act + e) = o;
}

// ---------------- projection ----------------------------------------------
__global__ __launch_bounds__(256) void proj_kernel(
    const unsigned short* __restrict__ act, const float* __restrict__ w,
    const float* __restrict__ b, float* __restrict__ out) {
  int v = blockIdx.x * 256 + threadIdx.x;
  const short8* p = reinterpret_cast<const short8*>(act + (size_t)v * 16);
  short8 a0 = p[0], a1 = p[1];
  float s = b[0];
  #pragma unroll
  for (int k = 0; k < 8; ++k) s = fmaf(bf2f((unsigned short)a0[k]), w[k], s);
  #pragma unroll
  for (int k = 0; k < 8; ++k) s = fmaf(bf2f((unsigned short)a1[k]), w[8 + k], s);
  out[v] = s;
}

extern "C" void kernel_launch(void* const* d_in, const int* in_sizes, int n_in,
                              void* d_out, int out_size, void* d_ws, size_t ws_size,
                              hipStream_t stream) {
  const float* x      = (const float*)d_in[0];
  const float* w_emb  = (const float*)d_in[1];
  const float* b_emb  = (const float*)d_in[2];
  const float* w1     = (const float*)d_in[3];
  const float* b1     = (const float*)d_in[4];
  const float* g1     = (const float*)d_in[5];
  const float* be1    = (const float*)d_in[6];
  const float* w2     = (const float*)d_in[7];
  const float* b2     = (const float*)d_in[8];
  const float* g2     = (const float*)d_in[9];
  const float* be2    = (const float*)d_in[10];
  const float* w3     = (const float*)d_in[11];
  const float* b3     = (const float*)d_in[12];
  const float* g3     = (const float*)d_in[13];
  const float* be3    = (const float*)d_in[14];
  const float* w_proj = (const float*)d_in[15];
  const float* b_proj = (const float*)d_in[16];

  char* ws = (char*)d_ws;
  unsigned short* ACT = (unsigned short*)(ws + ACT_OFF);
  float* CONV = (float*)(ws + CONV_OFF);
  short8* WB = (short8*)(ws + WB_OFF);
  unsigned short* ZP = (unsigned short*)(ws + ZP_OFF);
  float* STATS = (float*)(ws + STATS_OFF);
  float* PART = (float*)(ws + PART_OFF);
  float* out = (float*)d_out;

  zero_misc<<<1, 64, 0, stream>>>((float*)ZP);
  embed_kernel<<<VOL / 256, 256, 0, stream>>>(x, w_emb, b_emb, ACT);

  // layer 1: 16 -> 16
  wtrans_mfma<16, 16><<<(125 * 3 * 1 * 64 + 255) / 256, 256, 0, stream>>>(w1, WB);
  conv4d_mfma<16, 16><<<VOL / 16, 64, 0, stream>>>(ACT, WB, b1, CONV, ZP);
  bn_stats1<16><<<256, 256, 0, stream>>>(CONV, PART);
  bn_stats2<16><<<1, 64, 0, stream>>>(PART, g1, be1, STATS);
  bn_apply<16><<<VOL * 16 / 2048, 256, 0, stream>>>(CONV, STATS, ACT);

  // layer 2: 16 -> 32
  wtrans_mfma<16, 32><<<(125 * 3 * 2 * 64 + 255) / 256, 256, 0, stream>>>(w2, WB);
  conv4d_mfma<16, 32><<<VOL / 16, 64, 0, stream>>>(ACT, WB, b2, CONV, ZP);
  bn_stats1<32><<<256, 256, 0, stream>>>(CONV, PART);
  bn_stats2<32><<<1, 64, 0, stream>>>(PART, g2, be2, STATS);
  bn_apply<32><<<VOL * 32 / 2048, 256, 0, stream>>>(CONV, STATS, ACT);

  // layer 3: 32 -> 16
  wtrans_mfma<32, 16><<<(125 * 5 * 1 * 64 + 255) / 256, 256, 0, stream>>>(w3, WB);
  conv4d_mfma<32, 16><<<VOL / 16, 64, 0, stream>>>(ACT, WB, b3, CONV, ZP);
  bn_stats1<16><<<256, 256, 0, stream>>>(CONV, PART);
  bn_stats2<16><<<1, 64, 0, stream>>>(PART, g3, be3, STATS);
  bn_apply<16><<<VOL * 16 / 2048, 256, 0, stream>>>(CONV, STATS, ACT);

  proj_kernel<<<VOL / 256, 256, 0, stream>>>(ACT, w_proj, b_proj, out);
}